// Round 1
// baseline (427.087 us; speedup 1.0000x reference)
//
#include <hip/hip_runtime.h>
#include <stdint.h>

typedef short short8 __attribute__((ext_vector_type(8)));
typedef float f32x16 __attribute__((ext_vector_type(16)));
typedef unsigned int uint;

#define NREG 49
#define NQ   100
#define CC   256
#define LSTR 72                    // LDS row stride in bf16 elems (64 + 8 pad, 144 B)
#define OUT_POS_OFF 5017600        // 4*49*100*256
#define MFMA_BF16 __builtin_amdgcn_mfma_f32_32x32x16_bf16

__device__ __forceinline__ uint16_t f2bf_rne(float x){
    uint u = __float_as_uint(x);
    u += 0x7fffu + ((u >> 16) & 1u);
    return (uint16_t)(u >> 16);
}
__device__ __forceinline__ float bf2f(uint16_t b){
    return __uint_as_float(((uint)b) << 16);
}

// ---------------------------------------------------------------------------
// Kernel 0: precompute Q fragments (bf16 hi/lo) in exact 32x32x16 B-operand
// order: frag = qt*16 + k ; per lane 16B hi + 16B lo.
//   B[k=c][n=q]: lane holds Q[q = qt*32 + (lane&31)][c = k*16 + (lane>>5)*8 + j]
// ---------------------------------------------------------------------------
__global__ __launch_bounds__(512) void qfrag_kernel(const float* __restrict__ Qg,
                                                    uint4* __restrict__ qf){
    int gid  = blockIdx.x * 512 + threadIdx.x;   // 0..4095
    int lane = gid & 63;
    int frag = gid >> 6;                         // 0..63
    int k    = frag & 15;
    int qt   = frag >> 4;
    int q    = qt * 32 + (lane & 31);
    int c0   = k * 16 + (lane >> 5) * 8;
    float v[8];
#pragma unroll
    for (int j = 0; j < 8; ++j) v[j] = (q < NQ) ? Qg[q * CC + c0 + j] : 0.f;
    uint hu[4], lu[4];
#pragma unroll
    for (int j = 0; j < 4; ++j){
        uint16_t h0 = f2bf_rne(v[2*j]), h1 = f2bf_rne(v[2*j+1]);
        uint16_t l0 = f2bf_rne(v[2*j]   - bf2f(h0));
        uint16_t l1 = f2bf_rne(v[2*j+1] - bf2f(h1));
        hu[j] = (uint)h0 | ((uint)h1 << 16);
        lu[j] = (uint)l0 | ((uint)l1 << 16);
    }
    qf[(size_t)gid * 2]     = make_uint4(hu[0], hu[1], hu[2], hu[3]);
    qf[(size_t)gid * 2 + 1] = make_uint4(lu[0], lu[1], lu[2], lu[3]);
}

// ---------------------------------------------------------------------------
// Main fused attention kernel: 1 workgroup per (b, region), 512 threads.
// ---------------------------------------------------------------------------
__global__ __launch_bounds__(512, 2) void attn_kernel(
        const float* __restrict__ img, const float* __restrict__ Qg,
        const uint4* __restrict__ qf, float* __restrict__ out)
{
    __shared__ uint16_t sRT[256 * LSTR];   // r chunk, bf16, transposed [c][s]  36864 B
    __shared__ uint16_t sP [128 * LSTR];   // P chunk, bf16, [q][s]             18432 B
    __shared__ float    sL [128];          // softmax denominators

    const int tid = threadIdx.x;
    const int bn  = blockIdx.x;            // 0..195
    const int rr  = bn % NREG;
    const int bb  = bn / NREG;
    const int gh  = rr / 7, gw = rr % 7;

    if (bn == 0 && tid < NREG){            // positions output (row-major grid)
        out[OUT_POS_OFF + 2 * tid]     = (float)((tid / 7) / 7.0);
        out[OUT_POS_OFF + 2 * tid + 1] = (float)((tid % 7) / 7.0);
    }
    if (tid < 128) sL[tid] = 0.f;

    const int lane = tid & 63, w = tid >> 6;
    const int l31  = lane & 31, lh = lane >> 5;
    const int st = w & 1, qt = w >> 1;     // GEMM1 roles: s-tile, q-tile
    const int mp = w & 1, cq = w >> 1;     // GEMM2 roles: q-half, c-quarter

    // region base: pixel (hr,wr) lives at rbase + (hr*224 + wr)*256
    const float* rbase = img + ((size_t)(bb * 224 + gh * 32) * 224 + gw * 32) * CC;

    f32x16 acc00, acc01, acc10, acc11;
#pragma unroll
    for (int i = 0; i < 16; ++i){ acc00[i]=0.f; acc01[i]=0.f; acc10[i]=0.f; acc11[i]=0.f; }
    float lp = 0.f;
    const int qq = qt * 32 + l31;          // this lane's q column in GEMM1

    union V8 { uint u[4]; short8 v; };

    for (int ch = 0; ch < 16; ++ch){
        const int s0 = ch * 64;

        // ---- stage rhT[c][s] (bf16, RNE) via column-order global re-reads ----
#pragma unroll
        for (int p = 0; p < 4; ++p){
            int idx = tid + (p << 9);
            int c   = idx & 255;
            int sb  = idx >> 8;            // 0..7
            int s   = s0 + sb * 8;
            int hr  = s >> 5, wr = s & 31; // 8 consecutive s stay in one hr row
            const float* gp = rbase + (hr * 224 + wr) * CC + c;
            uint pk0, pk1, pk2, pk3;
            {
                uint16_t e0 = f2bf_rne(gp[0*CC]), e1 = f2bf_rne(gp[1*CC]);
                uint16_t e2 = f2bf_rne(gp[2*CC]), e3 = f2bf_rne(gp[3*CC]);
                uint16_t e4 = f2bf_rne(gp[4*CC]), e5 = f2bf_rne(gp[5*CC]);
                uint16_t e6 = f2bf_rne(gp[6*CC]), e7 = f2bf_rne(gp[7*CC]);
                pk0 = (uint)e0 | ((uint)e1 << 16);
                pk1 = (uint)e2 | ((uint)e3 << 16);
                pk2 = (uint)e4 | ((uint)e5 << 16);
                pk3 = (uint)e6 | ((uint)e7 << 16);
            }
            *(uint4*)&sRT[c * LSTR + sb * 8] = make_uint4(pk0, pk1, pk2, pk3);
        }

        // ---- GEMM1: scores^T[s][q] = r · q  (3-pass bf16 split) ----
        f32x16 a1;
#pragma unroll
        for (int i = 0; i < 16; ++i) a1[i] = 0.f;
        {
            // wave's s-tile is exactly one pixel row: hr = s0/32 + st, wr = l31
            const float* ar = rbase + (((s0 >> 5) + st) * 224 + l31) * CC;
            if (qf != nullptr){
#pragma unroll
                for (int k = 0; k < 16; ++k){
                    int c0 = k * 16 + lh * 8;
                    float4 v0 = *(const float4*)(ar + c0);
                    float4 v1 = *(const float4*)(ar + c0 + 4);
                    float vv[8] = {v0.x, v0.y, v0.z, v0.w, v1.x, v1.y, v1.z, v1.w};
                    V8 rh, rl;
#pragma unroll
                    for (int j = 0; j < 4; ++j){
                        uint u0 = __float_as_uint(vv[2*j]);
                        uint u1 = __float_as_uint(vv[2*j+1]);
                        rh.u[j] = (u0 >> 16) | (u1 & 0xFFFF0000u);      // trunc hi
                        float r0 = vv[2*j]   - __uint_as_float(u0 & 0xFFFF0000u);
                        float r1 = vv[2*j+1] - __uint_as_float(u1 & 0xFFFF0000u);
                        rl.u[j] = (__float_as_uint(r0) >> 16) |
                                  (__float_as_uint(r1) & 0xFFFF0000u);  // trunc lo
                    }
                    const uint4* qp = qf + ((size_t)((qt * 16 + k) * 64 + lane)) * 2;
                    V8 qh, ql;
                    uint4 t0 = qp[0], t1 = qp[1];
                    qh.u[0]=t0.x; qh.u[1]=t0.y; qh.u[2]=t0.z; qh.u[3]=t0.w;
                    ql.u[0]=t1.x; ql.u[1]=t1.y; ql.u[2]=t1.z; ql.u[3]=t1.w;
                    a1 = MFMA_BF16(rh.v, qh.v, a1, 0, 0, 0);
                    a1 = MFMA_BF16(rh.v, ql.v, a1, 0, 0, 0);
                    a1 = MFMA_BF16(rl.v, qh.v, a1, 0, 0, 0);
                }
            } else {
                const float* qrow = Qg + qq * CC;
                const bool qok = qq < NQ;
#pragma unroll
                for (int k = 0; k < 16; ++k){
                    int c0 = k * 16 + lh * 8;
                    float4 v0 = *(const float4*)(ar + c0);
                    float4 v1 = *(const float4*)(ar + c0 + 4);
                    float vv[8] = {v0.x, v0.y, v0.z, v0.w, v1.x, v1.y, v1.z, v1.w};
                    V8 rh, rl, qh, ql;
#pragma unroll
                    for (int j = 0; j < 4; ++j){
                        uint u0 = __float_as_uint(vv[2*j]);
                        uint u1 = __float_as_uint(vv[2*j+1]);
                        rh.u[j] = (u0 >> 16) | (u1 & 0xFFFF0000u);
                        float r0 = vv[2*j]   - __uint_as_float(u0 & 0xFFFF0000u);
                        float r1 = vv[2*j+1] - __uint_as_float(u1 & 0xFFFF0000u);
                        rl.u[j] = (__float_as_uint(r0) >> 16) |
                                  (__float_as_uint(r1) & 0xFFFF0000u);
                        float qa = qok ? qrow[c0 + 2*j]     : 0.f;
                        float qb = qok ? qrow[c0 + 2*j + 1] : 0.f;
                        uint16_t h0 = f2bf_rne(qa), h1 = f2bf_rne(qb);
                        uint16_t g0 = f2bf_rne(qa - bf2f(h0));
                        uint16_t g1 = f2bf_rne(qb - bf2f(h1));
                        qh.u[j] = (uint)h0 | ((uint)h1 << 16);
                        ql.u[j] = (uint)g0 | ((uint)g1 << 16);
                    }
                    a1 = MFMA_BF16(rh.v, qh.v, a1, 0, 0, 0);
                    a1 = MFMA_BF16(rh.v, ql.v, a1, 0, 0, 0);
                    a1 = MFMA_BF16(rl.v, qh.v, a1, 0, 0, 0);
                }
            }
        }

        // ---- exp(score - 40) -> bf16 P[q][s], accumulate l ----
        // C/D map (32x32): col=q=lane&31, row=s=(reg&3)+8*(reg>>2)+4*lh
#pragma unroll
        for (int g2 = 0; g2 < 4; ++g2){
            uint16_t e[4];
#pragma unroll
            for (int r2 = 0; r2 < 4; ++r2){
                float sc = a1[g2 * 4 + r2];
                float pv = exp2f(sc * 1.4426950408889634f - 57.70780163555852f);
                e[r2] = f2bf_rne(pv);
                lp += bf2f(e[r2]);                     // l consistent with bf16 P
            }
            int sl = st * 32 + g2 * 8 + lh * 4;
            *(uint2*)&sP[qq * LSTR + sl] =
                make_uint2((uint)e[0] | ((uint)e[1] << 16),
                           (uint)e[2] | ((uint)e[3] << 16));
        }
        __syncthreads();

        // ---- GEMM2: O[q][c] += P[q][s] * r[s][c] ----
#pragma unroll
        for (int k = 0; k < 4; ++k){
            int so = k * 16 + lh * 8;
            short8 A0 = *(const short8*)&sP [(mp * 64      + l31) * LSTR + so];
            short8 A1 = *(const short8*)&sP [(mp * 64 + 32 + l31) * LSTR + so];
            short8 B0 = *(const short8*)&sRT[(cq * 64      + l31) * LSTR + so];
            short8 B1 = *(const short8*)&sRT[(cq * 64 + 32 + l31) * LSTR + so];
            acc00 = MFMA_BF16(A0, B0, acc00, 0, 0, 0);
            acc01 = MFMA_BF16(A0, B1, acc01, 0, 0, 0);
            acc10 = MFMA_BF16(A1, B0, acc10, 0, 0, 0);
            acc11 = MFMA_BF16(A1, B1, acc11, 0, 0, 0);
        }
        __syncthreads();
    }

    // ---- reduce l, normalize, store ----
    atomicAdd(&sL[qq], lp);
    __syncthreads();

    float* ob = out + (size_t)bn * (NQ * CC);
    const int c0 = cq * 64 + l31;
#pragma unroll
    for (int r = 0; r < 16; ++r){
        int row = (r & 3) + 8 * (r >> 2) + 4 * lh;
        int q0 = mp * 64 + row;
        int q1 = q0 + 32;
        if (q0 < NQ){
            float inv = 1.0f / sL[q0];
            ob[q0 * CC + c0]      = acc00[r] * inv;
            ob[q0 * CC + c0 + 32] = acc01[r] * inv;
        }
        if (q1 < NQ){
            float inv = 1.0f / sL[q1];
            ob[q1 * CC + c0]      = acc10[r] * inv;
            ob[q1 * CC + c0 + 32] = acc11[r] * inv;
        }
    }
}

extern "C" void kernel_launch(void* const* d_in, const int* in_sizes, int n_in,
                              void* d_out, int out_size, void* d_ws, size_t ws_size,
                              hipStream_t stream){
    const float* img = (const float*)d_in[0];
    const float* Qg  = (const float*)d_in[1];
    float* out = (float*)d_out;
    uint4* qf = nullptr;
    if (ws_size >= 131072){
        qf = (uint4*)d_ws;
        qfrag_kernel<<<8, 512, 0, stream>>>(Qg, qf);
    }
    attn_kernel<<<196, 512, 0, stream>>>(img, Qg, qf, out);
}